// Round 18
// baseline (115.962 us; speedup 1.0000x reference)
//
#include <hip/hip_runtime.h>

typedef __attribute__((ext_vector_type(4))) float f32x4;
typedef __attribute__((ext_vector_type(16))) float f32x16;
typedef __attribute__((ext_vector_type(4))) unsigned short u16x4;
typedef __attribute__((ext_vector_type(8))) unsigned short u16x8;
typedef __attribute__((ext_vector_type(4))) unsigned int u32x4;
typedef __attribute__((ext_vector_type(8))) __bf16 bf16x8;

#define SZX_E ((size_t)4 * 2048 * 512)  // elements per activation tensor
#define SZW_E ((size_t)512 * 512)

__device__ __forceinline__ unsigned short f2bf(float f) {
  unsigned int u = __builtin_bit_cast(unsigned int, f);
  u += 0x7fffu + ((u >> 16) & 1u);
  return (unsigned short)(u >> 16);
}

__device__ __forceinline__ bf16x8 ld_bf8(const unsigned short* p) {
  return __builtin_bit_cast(bf16x8, *(const u16x8*)p);
}

__device__ __forceinline__ f32x4 mfma16(bf16x8 a, bf16x8 b, f32x4 c) {
  return __builtin_amdgcn_mfma_f32_16x16x32_bf16(a, b, c, 0, 0, 0);
}

__device__ __forceinline__ f32x16 mfma32(bf16x8 a, bf16x8 b, f32x16 c) {
  return __builtin_amdgcn_mfma_f32_32x32x16_bf16(a, b, c, 0, 0, 0);
}

__device__ __forceinline__ unsigned int cvt_pk_bf16(float lo, float hi) {
  unsigned int r;
  asm("v_cvt_pk_bf16_f32 %0, %1, %2" : "=v"(r) : "v"(lo), "v"(hi));
  return r;
}

__device__ __forceinline__ void plane32_swap(unsigned int& a, unsigned int& b) {
  asm("v_permlane32_swap_b32 %0, %1" : "+v"(a), "+v"(b));
}

// raw v_exp_f32 (2^x); args bounded (|scores*log2e| < ~10) -> equals exp2f.
__device__ __forceinline__ float exp2_fast(float x) {
  float r;
  asm("v_exp_f32 %0, %1" : "=v"(r) : "v"(x));
  return r;
}

// async global->LDS, 16B per lane; LDS dest = WAVE-UNIFORM base, HW adds lane*16
__device__ __forceinline__ void gload16(const void* g, void* l) {
  __builtin_amdgcn_global_load_lds(
      (const __attribute__((address_space(1))) unsigned int*)g,
      (__attribute__((address_space(3))) unsigned int*)l, 16, 0, 0);
}

// ---------------- fused fp32 -> bf16 convert (all 7 tensors, one launch) ----------------
__global__ __launch_bounds__(256) void cvt_all(const float* __restrict__ q_,
                                               const float* __restrict__ k_,
                                               const float* __restrict__ v_,
                                               const float* __restrict__ wq_,
                                               const float* __restrict__ wk_,
                                               const float* __restrict__ wv_,
                                               const float* __restrict__ wo_,
                                               unsigned short* __restrict__ out) {
  const int bq = blockIdx.x;
  const float* src;
  size_t segbase, li;
  if (bq < 12288) {
    const int s = bq >> 12;
    src = (s == 0) ? q_ : (s == 1) ? k_ : v_;
    li = (size_t)(bq & 4095) * 256 + threadIdx.x;
    segbase = (size_t)s * 4194304;
  } else {
    const int s = (bq - 12288) >> 8;
    src = (s == 0) ? wq_ : (s == 1) ? wk_ : (s == 2) ? wv_ : wo_;
    li = (size_t)((bq - 12288) & 255) * 256 + threadIdx.x;
    segbase = 12582912 + (size_t)s * 262144;
  }
  const f32x4 v = *(const f32x4*)(src + li * 4);
  u16x4 r;
  r[0] = f2bf(v[0]); r[1] = f2bf(v[1]); r[2] = f2bf(v[2]); r[3] = f2bf(v[3]);
  *(u16x4*)(out + segbase + li * 4) = r;
}

// ---------------- fused QKV GEMM: z = 0/1/2 -> Q/K/V projection (r12 proven path) ----------------
__global__ __launch_bounds__(256) void gemm_qkv(const unsigned short* __restrict__ base,
                                                const float* __restrict__ bq,
                                                const float* __restrict__ bk,
                                                const float* __restrict__ bv,
                                                unsigned short* __restrict__ outb) {
  __shared__ unsigned short Asb[2][4096];
  __shared__ unsigned short Bsb[2][4096];
  const int z = blockIdx.z;
  const unsigned short* A = base + (size_t)z * SZX_E;
  const unsigned short* Bw = base + 3 * SZX_E + (size_t)z * SZW_E;
  const float* bias = (z == 0) ? bq : (z == 1) ? bk : bv;

  const int tid = threadIdx.x;
  const int l = tid & 63;
  const int w = tid >> 6;
  const int g = l >> 4;
  const int lr = l & 15;
  const int mB = blockIdx.y * 128;
  const int nB = blockIdx.x * 128;
  const int m0 = (w >> 1) * 64;
  const int n0 = (w & 1) * 64;
  const int ubase = tid & ~63;

  auto stage = [&](int bufi, int kk) {
#pragma unroll
    for (int i = 0; i < 2; i++) {
      const int idx = i * 256 + tid;
      const int ub = i * 256 + ubase;
      const int r = idx >> 2, c = idx & 3;
      gload16((const char*)A + ((size_t)(mB + r) * 512 + kk + c * 8) * 2,
              (char*)&Asb[bufi][0] + ub * 16);
      gload16((const char*)Bw + ((size_t)(nB + r) * 512 + kk + c * 8) * 2,
              (char*)&Bsb[bufi][0] + ub * 16);
    }
  };

  f32x4 acc[4][4];
#pragma unroll
  for (int i = 0; i < 4; i++)
#pragma unroll
    for (int j = 0; j < 4; j++) acc[i][j] = f32x4{0.f, 0.f, 0.f, 0.f};

  stage(0, 0);
  __syncthreads();
  int buf = 0;

  for (int ks = 0; ks < 16; ++ks) {
    if (ks < 15) stage(buf ^ 1, (ks + 1) * 32);
    bf16x8 af[4], bfr[4];
#pragma unroll
    for (int t = 0; t < 4; t++) {
      af[t] = ld_bf8(&Asb[buf][(m0 + t * 16 + lr) * 32 + g * 8]);
      bfr[t] = ld_bf8(&Bsb[buf][(n0 + t * 16 + lr) * 32 + g * 8]);
    }
#pragma unroll
    for (int i = 0; i < 4; i++)
#pragma unroll
      for (int j = 0; j < 4; j++)
        acc[i][j] = mfma16(af[i], bfr[j], acc[i][j]);
    __syncthreads();
    buf ^= 1;
  }

  unsigned short* outz = outb + (size_t)z * SZX_E;  // Qp / Kp / Vt
#pragma unroll
  for (int j = 0; j < 4; j++) {
    const int n = nB + n0 + j * 16 + lr;
    const float bn = bias[n];
#pragma unroll
    for (int i = 0; i < 4; i++) {
#pragma unroll
      for (int r = 0; r < 4; r++) {
        const int m = mB + m0 + i * 16 + g * 4 + r;
        const float v = acc[i][j][r] + bn;
        if (z < 2) {
          outz[(size_t)m * 512 + n] = f2bf(v);
        } else {
          const int bb = m >> 11, s = m & 2047;
          const int hh = n >> 6, d = n & 63;
          outz[((size_t)((bb * 8 + hh) * 64 + d) << 11) + s] = f2bf(v);
        }
      }
    }
  }
}

// ---------------- output GEMM: fp32 out + bias (r12 proven path) ----------------
__global__ __launch_bounds__(256) void gemm_o(const unsigned short* __restrict__ A,
                                              const unsigned short* __restrict__ Bw,
                                              const float* __restrict__ bias,
                                              float* __restrict__ Cout) {
  __shared__ unsigned short Asb[2][4096];
  __shared__ unsigned short Bsb[2][4096];
  const int tid = threadIdx.x;
  const int l = tid & 63;
  const int w = tid >> 6;
  const int g = l >> 4;
  const int lr = l & 15;
  const int mB = blockIdx.y * 128;
  const int nB = blockIdx.x * 128;
  const int m0 = (w >> 1) * 64;
  const int n0 = (w & 1) * 64;
  const int ubase = tid & ~63;

  auto stage = [&](int bufi, int kk) {
#pragma unroll
    for (int i = 0; i < 2; i++) {
      const int idx = i * 256 + tid;
      const int ub = i * 256 + ubase;
      const int r = idx >> 2, c = idx & 3;
      gload16((const char*)A + ((size_t)(mB + r) * 512 + kk + c * 8) * 2,
              (char*)&Asb[bufi][0] + ub * 16);
      gload16((const char*)Bw + ((size_t)(nB + r) * 512 + kk + c * 8) * 2,
              (char*)&Bsb[bufi][0] + ub * 16);
    }
  };

  f32x4 acc[4][4];
#pragma unroll
  for (int i = 0; i < 4; i++)
#pragma unroll
    for (int j = 0; j < 4; j++) acc[i][j] = f32x4{0.f, 0.f, 0.f, 0.f};

  stage(0, 0);
  __syncthreads();
  int buf = 0;

  for (int ks = 0; ks < 16; ++ks) {
    if (ks < 15) stage(buf ^ 1, (ks + 1) * 32);
    bf16x8 af[4], bfr[4];
#pragma unroll
    for (int t = 0; t < 4; t++) {
      af[t] = ld_bf8(&Asb[buf][(m0 + t * 16 + lr) * 32 + g * 8]);
      bfr[t] = ld_bf8(&Bsb[buf][(n0 + t * 16 + lr) * 32 + g * 8]);
    }
#pragma unroll
    for (int i = 0; i < 4; i++)
#pragma unroll
      for (int j = 0; j < 4; j++)
        acc[i][j] = mfma16(af[i], bfr[j], acc[i][j]);
    __syncthreads();
    buf ^= 1;
  }

#pragma unroll
  for (int j = 0; j < 4; j++) {
    const int n = nB + n0 + j * 16 + lr;
    const float bn = bias[n];
#pragma unroll
    for (int i = 0; i < 4; i++) {
#pragma unroll
      for (int r = 0; r < 4; r++) {
        const int m = mB + m0 + i * 16 + g * 4 + r;
        Cout[(size_t)m * 512 + n] = acc[i][j][r] + bn;
      }
    }
  }
}

// ---------------- flash attention: KV-split waves (2 qg x 2 kh), zero-shift softmax ----------------
// Block = 4 waves sharing ONE staged 64-kv K/V stream; wave (qg,kh) computes kv rows
// [kh*32, kh*32+32) of every tile for q-rows [qb*64+qg*32, +32). 1024 blocks -> 4 blocks/CU
// -> 4 waves/SIMD (2x r17's TLP). Zero-shift => cross-kh combine is a plain add in LDS
// (overlaid on dead K_lds/V_lds).
__global__ __launch_bounds__(256, 4) void attn_kernel(const unsigned short* __restrict__ Qp,
                                                      const unsigned short* __restrict__ Kp,
                                                      const unsigned short* __restrict__ Vt,
                                                      const float* __restrict__ rel_emb,
                                                      unsigned short* __restrict__ At) {
  __shared__ float bias_s[257];
  __shared__ unsigned short K_lds[2][4096];  // [64 kv][64 d], chunk-swizzled
  __shared__ unsigned short V_lds[2][4096];  // [64 d][64 s], chunk-swizzled
  const int bid0 = blockIdx.x;
  const int lg = (bid0 & 7) * 128 + (bid0 >> 3);  // XCD-bijective remap (1024 % 8 == 0)
  const int qb = lg & 31;
  const int h = (lg >> 5) & 7;
  const int b = lg >> 8;
  const int tid = threadIdx.x;
  const int lane = tid & 63, w = tid >> 6;
  const int qg = w >> 1, kh = w & 1;
  const int hi = lane >> 5, q31 = lane & 31;
  const int q0w = qb * 64 + qg * 32;
  const int tq = q0w + q31;  // this lane's q (score column)
  const float SCL = 0.125f * 1.44269504f;

  const char* kstage = (const char*)Kp + ((size_t)b * 2048 * 512 + h * 64) * 2;
  const char* vstage = (const char*)Vt + ((size_t)(b * 8 + h) * 64 * 2048) * 2;

  // 4 waves cooperatively stage the full 64-kv tile (K: 8KB, V: 8KB); 2+2 chunks/wave.
  auto stage = [&](int bufi, int s0n) {
#pragma unroll
    for (int ii = 0; ii < 2; ii++) {
      const int ins = w * 2 + ii;               // 0..7
      const int rr = ins * 8 + (lane >> 3);     // row 0..63
      const int ch = (lane & 7) ^ (rr & 7);     // inverse-swizzled 16B chunk
      gload16(kstage + (size_t)(s0n + rr) * 1024 + ch * 16,
              (char*)&K_lds[bufi][0] + ins * 1024);
      gload16(vstage + (size_t)rr * 4096 + (size_t)s0n * 2 + ch * 16,
              (char*)&V_lds[bufi][0] + ins * 1024);
    }
  };

  for (int i = tid; i < 257; i += 256) bias_s[i] = rel_emb[i * 8 + h] * 1.44269504f;
  stage(0, 0);
  __syncthreads();
  const float bias_lo = bias_s[0], bias_hi = bias_s[256];

  const unsigned short* qptr = Qp + (size_t)(b * 2048 + tq) * 512 + h * 64 + hi * 8;
  const bf16x8 qf0 = ld_bf8(qptr);
  const bf16x8 qf1 = ld_bf8(qptr + 16);
  const bf16x8 qf2 = ld_bf8(qptr + 32);
  const bf16x8 qf3 = ld_bf8(qptr + 48);

  const f32x16 z16 = {0.f, 0.f, 0.f, 0.f, 0.f, 0.f, 0.f, 0.f,
                      0.f, 0.f, 0.f, 0.f, 0.f, 0.f, 0.f, 0.f};
  f32x16 o_lo = z16, o_hi = z16;  // [q rows][d 0..31 / 32..63], col = d = q31
  float l_run = 0.f;
  int buf = 0;
  const int kvb = kh * 32;  // this wave's kv-half within each tile
  const int rswz = q31 & 7;

  for (int t = 0; t < 32; ++t) {
    const int s0 = t * 64;
    if (t != 31) stage(buf ^ 1, s0 + 64);

    // ---- QK^T (swapped): D[kv32][q32]; A = K rows kvb+q31 ----
    const unsigned short* kb = &K_lds[buf][0];
    f32x16 sa;
    sa = mfma32(ld_bf8(kb + (kvb + q31) * 64 + (((0 + hi) ^ rswz) << 3)), qf0, z16);
    sa = mfma32(ld_bf8(kb + (kvb + q31) * 64 + (((2 + hi) ^ rswz) << 3)), qf1, sa);
    sa = mfma32(ld_bf8(kb + (kvb + q31) * 64 + (((4 + hi) ^ rswz) << 3)), qf2, sa);
    sa = mfma32(ld_bf8(kb + (kvb + q31) * 64 + (((6 + hi) ^ rswz) << 3)), qf3, sa);

    // ---- V B-frags: vf[oh][kc] = V[kv = kvb+kc*16+hi*8 ..][d = oh*32+q31] ----
    const unsigned short* vb = &V_lds[buf][0];
    bf16x8 vf[2][2];
#pragma unroll
    for (int oh = 0; oh < 2; oh++)
#pragma unroll
      for (int kc = 0; kc < 2; kc++)
        vf[oh][kc] = ld_bf8(vb + (oh * 32 + q31) * 64 +
                            (((kh * 4 + kc * 2 + hi) ^ rswz) << 3));

    // ---- bias fold (zero-shift): out-of-band tiles keep raw scores ----
    const int relmin = q0w - s0 - 63;
    const int relmax = q0w + 31 - s0;
    float SCL2, off0;
    if (relmin >= 128 || relmax <= -128) {
      SCL2 = SCL;
      off0 = (relmin >= 128) ? bias_hi : bias_lo;
    } else {
#pragma unroll
      for (int r = 0; r < 16; r++) {
        const int rowA = (r & 3) + 8 * (r >> 2) + 4 * hi;
        const int rA = tq - (s0 + kvb) - rowA;
        const int iA = (rA < -128 ? -128 : (rA > 128 ? 128 : rA)) + 128;
        sa[r] = fmaf(sa[r], SCL, bias_s[iA]);
      }
      SCL2 = 1.f;
      off0 = 0.f;
    }

    // ---- exp2 + sum (zero-shift) ----
#pragma unroll
    for (int r = 0; r < 16; r++) sa[r] = exp2_fast(fmaf(sa[r], SCL2, off0));
    float s4[4];
#pragma unroll
    for (int i = 0; i < 4; i++)
      s4[i] = (sa[i] + sa[i + 4]) + (sa[i + 8] + sa[i + 12]);
    float ps = (s4[0] + s4[1]) + (s4[2] + s4[3]);
    ps += __shfl_xor(ps, 32, 64);
    l_run += ps;

    // ---- P -> PV A-frags (2 k-chunks of 16 kv) ----
    bf16x8 pa[2];
#pragma unroll
    for (int kc = 0; kc < 2; kc++) {
      const int c8 = kc * 8;
      unsigned int a0 = cvt_pk_bf16(sa[c8 + 0], sa[c8 + 1]);
      unsigned int b0 = cvt_pk_bf16(sa[c8 + 4], sa[c8 + 5]);
      unsigned int a1 = cvt_pk_bf16(sa[c8 + 2], sa[c8 + 3]);
      unsigned int b1 = cvt_pk_bf16(sa[c8 + 6], sa[c8 + 7]);
      plane32_swap(a0, b0);
      plane32_swap(a1, b1);
      pa[kc] = __builtin_bit_cast(bf16x8, u32x4{a0, a1, b0, b1});
    }

    // ---- PV over this wave's 32 kv ----
    o_lo = mfma32(pa[0], vf[0][0], o_lo);
    o_hi = mfma32(pa[0], vf[1][0], o_hi);
    o_lo = mfma32(pa[1], vf[0][1], o_lo);
    o_hi = mfma32(pa[1], vf[1][1], o_hi);

    __syncthreads();
    buf ^= 1;
  }

  // ---- cross-kh combine (plain add; zero-shift => no LSE merge) ----
  float* o_comb = (float*)&K_lds[0][0];   // [2 qg][32 q][64 d] fp32 = 16 KB (= K_lds)
  float* l_comb = (float*)&V_lds[0][0];   // [2 qg][32 q]
  if (kh == 1) {
#pragma unroll
    for (int r2 = 0; r2 < 16; r2++) {
      const int ro = (r2 & 3) + 8 * (r2 >> 2) + 4 * hi;
      o_comb[(qg * 32 + ro) * 64 + q31] = o_lo[r2];
      o_comb[(qg * 32 + ro) * 64 + 32 + q31] = o_hi[r2];
    }
    if (hi == 0) l_comb[qg * 32 + q31] = l_run;
  }
  __syncthreads();
  if (kh == 0) {
#pragma unroll
    for (int r2 = 0; r2 < 16; r2++) {
      const int ro = (r2 & 3) + 8 * (r2 >> 2) + 4 * hi;
      const float lsum = __shfl(l_run, ro, 64) + l_comb[qg * 32 + ro];
      const float rr = 1.f / lsum;
      const float v_lo = o_lo[r2] + o_comb[(qg * 32 + ro) * 64 + q31];
      const float v_hi = o_hi[r2] + o_comb[(qg * 32 + ro) * 64 + 32 + q31];
      unsigned short* op = At + (size_t)(b * 2048 + q0w + ro) * 512 + h * 64;
      op[q31] = f2bf(v_lo * rr);
      op[32 + q31] = f2bf(v_hi * rr);
    }
  }
}

// ---------------- host ----------------
extern "C" void kernel_launch(void* const* d_in, const int* in_sizes, int n_in,
                              void* d_out, int out_size, void* d_ws, size_t ws_size,
                              hipStream_t stream) {
  const float* query = (const float*)d_in[0];
  const float* key   = (const float*)d_in[1];
  const float* value = (const float*)d_in[2];
  const float* Wq = (const float*)d_in[3];
  const float* bq = (const float*)d_in[4];
  const float* Wk = (const float*)d_in[5];
  const float* bk = (const float*)d_in[6];
  const float* Wv = (const float*)d_in[7];
  const float* bv = (const float*)d_in[8];
  const float* Wo = (const float*)d_in[9];
  const float* bo = (const float*)d_in[10];
  const float* rel = (const float*)d_in[11];

  char* ws = (char*)d_ws;
  unsigned short* base = (unsigned short*)ws;       // xq xk xv | wq wk wv wo | ...
  unsigned short* wo = base + 3 * SZX_E + 3 * SZW_E;
  unsigned short* Qp = base + 3 * SZX_E + 4 * SZW_E;
  unsigned short* Kp = Qp + SZX_E;
  unsigned short* Vt = Kp + SZX_E;
  unsigned short* At = Vt + SZX_E;

  cvt_all<<<dim3(13312), dim3(256), 0, stream>>>(query, key, value, Wq, Wk, Wv, Wo, base);

  dim3 blk(256);
  gemm_qkv<<<dim3(4, 64, 3), blk, 0, stream>>>(base, bq, bk, bv, Qp);

  attn_kernel<<<dim3(1024), blk, 0, stream>>>(Qp, Kp, Vt, rel, At);

  gemm_o<<<dim3(4, 64), blk, 0, stream>>>(At, wo, bo, (float*)d_out);
}

// Round 19
// 104.814 us; speedup vs baseline: 1.1064x; 1.1064x over previous
//
#include <hip/hip_runtime.h>

typedef __attribute__((ext_vector_type(4))) float f32x4;
typedef __attribute__((ext_vector_type(16))) float f32x16;
typedef __attribute__((ext_vector_type(4))) unsigned short u16x4;
typedef __attribute__((ext_vector_type(8))) unsigned short u16x8;
typedef __attribute__((ext_vector_type(4))) unsigned int u32x4;
typedef __attribute__((ext_vector_type(8))) __bf16 bf16x8;

#define SZX_E ((size_t)4 * 2048 * 512)  // elements per activation tensor
#define SZW_E ((size_t)512 * 512)

__device__ __forceinline__ unsigned short f2bf(float f) {
  unsigned int u = __builtin_bit_cast(unsigned int, f);
  u += 0x7fffu + ((u >> 16) & 1u);
  return (unsigned short)(u >> 16);
}

__device__ __forceinline__ bf16x8 ld_bf8(const unsigned short* p) {
  return __builtin_bit_cast(bf16x8, *(const u16x8*)p);
}

__device__ __forceinline__ f32x4 mfma16(bf16x8 a, bf16x8 b, f32x4 c) {
  return __builtin_amdgcn_mfma_f32_16x16x32_bf16(a, b, c, 0, 0, 0);
}

__device__ __forceinline__ f32x16 mfma32(bf16x8 a, bf16x8 b, f32x16 c) {
  return __builtin_amdgcn_mfma_f32_32x32x16_bf16(a, b, c, 0, 0, 0);
}

__device__ __forceinline__ unsigned int cvt_pk_bf16(float lo, float hi) {
  unsigned int r;
  asm("v_cvt_pk_bf16_f32 %0, %1, %2" : "=v"(r) : "v"(lo), "v"(hi));
  return r;
}

__device__ __forceinline__ void plane32_swap(unsigned int& a, unsigned int& b) {
  asm("v_permlane32_swap_b32 %0, %1" : "+v"(a), "+v"(b));
}

// raw v_exp_f32 (2^x); args bounded (|scores*log2e| < ~10) -> equals exp2f.
__device__ __forceinline__ float exp2_fast(float x) {
  float r;
  asm("v_exp_f32 %0, %1" : "=v"(r) : "v"(x));
  return r;
}

// async global->LDS, 16B per lane; LDS dest = WAVE-UNIFORM base, HW adds lane*16
__device__ __forceinline__ void gload16(const void* g, void* l) {
  __builtin_amdgcn_global_load_lds(
      (const __attribute__((address_space(1))) unsigned int*)g,
      (__attribute__((address_space(3))) unsigned int*)l, 16, 0, 0);
}

// ---------------- fused fp32 -> bf16 convert (all 7 tensors, one launch) ----------------
__global__ __launch_bounds__(256) void cvt_all(const float* __restrict__ q_,
                                               const float* __restrict__ k_,
                                               const float* __restrict__ v_,
                                               const float* __restrict__ wq_,
                                               const float* __restrict__ wk_,
                                               const float* __restrict__ wv_,
                                               const float* __restrict__ wo_,
                                               unsigned short* __restrict__ out) {
  const int bq = blockIdx.x;
  const float* src;
  size_t segbase, li;
  if (bq < 12288) {
    const int s = bq >> 12;
    src = (s == 0) ? q_ : (s == 1) ? k_ : v_;
    li = (size_t)(bq & 4095) * 256 + threadIdx.x;
    segbase = (size_t)s * 4194304;
  } else {
    const int s = (bq - 12288) >> 8;
    src = (s == 0) ? wq_ : (s == 1) ? wk_ : (s == 2) ? wv_ : wo_;
    li = (size_t)((bq - 12288) & 255) * 256 + threadIdx.x;
    segbase = 12582912 + (size_t)s * 262144;
  }
  const f32x4 v = *(const f32x4*)(src + li * 4);
  u16x4 r;
  r[0] = f2bf(v[0]); r[1] = f2bf(v[1]); r[2] = f2bf(v[2]); r[3] = f2bf(v[3]);
  *(u16x4*)(out + segbase + li * 4) = r;
}

// ---------------- fused QKV GEMM: z = 0/1/2 -> Q/K/V projection (r12 proven path) ----------------
__global__ __launch_bounds__(256) void gemm_qkv(const unsigned short* __restrict__ base,
                                                const float* __restrict__ bq,
                                                const float* __restrict__ bk,
                                                const float* __restrict__ bv,
                                                unsigned short* __restrict__ outb) {
  __shared__ unsigned short Asb[2][4096];
  __shared__ unsigned short Bsb[2][4096];
  const int z = blockIdx.z;
  const unsigned short* A = base + (size_t)z * SZX_E;
  const unsigned short* Bw = base + 3 * SZX_E + (size_t)z * SZW_E;
  const float* bias = (z == 0) ? bq : (z == 1) ? bk : bv;

  const int tid = threadIdx.x;
  const int l = tid & 63;
  const int w = tid >> 6;
  const int g = l >> 4;
  const int lr = l & 15;
  const int mB = blockIdx.y * 128;
  const int nB = blockIdx.x * 128;
  const int m0 = (w >> 1) * 64;
  const int n0 = (w & 1) * 64;
  const int ubase = tid & ~63;

  auto stage = [&](int bufi, int kk) {
#pragma unroll
    for (int i = 0; i < 2; i++) {
      const int idx = i * 256 + tid;
      const int ub = i * 256 + ubase;
      const int r = idx >> 2, c = idx & 3;
      gload16((const char*)A + ((size_t)(mB + r) * 512 + kk + c * 8) * 2,
              (char*)&Asb[bufi][0] + ub * 16);
      gload16((const char*)Bw + ((size_t)(nB + r) * 512 + kk + c * 8) * 2,
              (char*)&Bsb[bufi][0] + ub * 16);
    }
  };

  f32x4 acc[4][4];
#pragma unroll
  for (int i = 0; i < 4; i++)
#pragma unroll
    for (int j = 0; j < 4; j++) acc[i][j] = f32x4{0.f, 0.f, 0.f, 0.f};

  stage(0, 0);
  __syncthreads();
  int buf = 0;

  for (int ks = 0; ks < 16; ++ks) {
    if (ks < 15) stage(buf ^ 1, (ks + 1) * 32);
    bf16x8 af[4], bfr[4];
#pragma unroll
    for (int t = 0; t < 4; t++) {
      af[t] = ld_bf8(&Asb[buf][(m0 + t * 16 + lr) * 32 + g * 8]);
      bfr[t] = ld_bf8(&Bsb[buf][(n0 + t * 16 + lr) * 32 + g * 8]);
    }
#pragma unroll
    for (int i = 0; i < 4; i++)
#pragma unroll
      for (int j = 0; j < 4; j++)
        acc[i][j] = mfma16(af[i], bfr[j], acc[i][j]);
    __syncthreads();
    buf ^= 1;
  }

  unsigned short* outz = outb + (size_t)z * SZX_E;  // Qp / Kp / Vt
#pragma unroll
  for (int j = 0; j < 4; j++) {
    const int n = nB + n0 + j * 16 + lr;
    const float bn = bias[n];
#pragma unroll
    for (int i = 0; i < 4; i++) {
#pragma unroll
      for (int r = 0; r < 4; r++) {
        const int m = mB + m0 + i * 16 + g * 4 + r;
        const float v = acc[i][j][r] + bn;
        if (z < 2) {
          outz[(size_t)m * 512 + n] = f2bf(v);
        } else {
          const int bb = m >> 11, s = m & 2047;
          const int hh = n >> 6, d = n & 63;
          outz[((size_t)((bb * 8 + hh) * 64 + d) << 11) + s] = f2bf(v);
        }
      }
    }
  }
}

// ---------------- output GEMM: fp32 out + bias (r12 proven path) ----------------
__global__ __launch_bounds__(256) void gemm_o(const unsigned short* __restrict__ A,
                                              const unsigned short* __restrict__ Bw,
                                              const float* __restrict__ bias,
                                              float* __restrict__ Cout) {
  __shared__ unsigned short Asb[2][4096];
  __shared__ unsigned short Bsb[2][4096];
  const int tid = threadIdx.x;
  const int l = tid & 63;
  const int w = tid >> 6;
  const int g = l >> 4;
  const int lr = l & 15;
  const int mB = blockIdx.y * 128;
  const int nB = blockIdx.x * 128;
  const int m0 = (w >> 1) * 64;
  const int n0 = (w & 1) * 64;
  const int ubase = tid & ~63;

  auto stage = [&](int bufi, int kk) {
#pragma unroll
    for (int i = 0; i < 2; i++) {
      const int idx = i * 256 + tid;
      const int ub = i * 256 + ubase;
      const int r = idx >> 2, c = idx & 3;
      gload16((const char*)A + ((size_t)(mB + r) * 512 + kk + c * 8) * 2,
              (char*)&Asb[bufi][0] + ub * 16);
      gload16((const char*)Bw + ((size_t)(nB + r) * 512 + kk + c * 8) * 2,
              (char*)&Bsb[bufi][0] + ub * 16);
    }
  };

  f32x4 acc[4][4];
#pragma unroll
  for (int i = 0; i < 4; i++)
#pragma unroll
    for (int j = 0; j < 4; j++) acc[i][j] = f32x4{0.f, 0.f, 0.f, 0.f};

  stage(0, 0);
  __syncthreads();
  int buf = 0;

  for (int ks = 0; ks < 16; ++ks) {
    if (ks < 15) stage(buf ^ 1, (ks + 1) * 32);
    bf16x8 af[4], bfr[4];
#pragma unroll
    for (int t = 0; t < 4; t++) {
      af[t] = ld_bf8(&Asb[buf][(m0 + t * 16 + lr) * 32 + g * 8]);
      bfr[t] = ld_bf8(&Bsb[buf][(n0 + t * 16 + lr) * 32 + g * 8]);
    }
#pragma unroll
    for (int i = 0; i < 4; i++)
#pragma unroll
      for (int j = 0; j < 4; j++)
        acc[i][j] = mfma16(af[i], bfr[j], acc[i][j]);
    __syncthreads();
    buf ^= 1;
  }

#pragma unroll
  for (int j = 0; j < 4; j++) {
    const int n = nB + n0 + j * 16 + lr;
    const float bn = bias[n];
#pragma unroll
    for (int i = 0; i < 4; i++) {
#pragma unroll
      for (int r = 0; r < 4; r++) {
        const int m = mB + m0 + i * 16 + g * 4 + r;
        Cout[(size_t)m * 512 + n] = acc[i][j][r] + bn;
      }
    }
  }
}

// ---------------- flash attention: r17 math, address-invariant restructure ----------------
// Identical layout/math to r17 (LDS-staged K/V, XCD swizzle, zero-shift softmax).
// Loop unrolled x2 with compile-time buf; LDS read offsets precomputed once; staging
// via 4 running global pointers advanced by constant stride (kills per-tile addr VALU).
__global__ __launch_bounds__(256, 2) void attn_kernel(const unsigned short* __restrict__ Qp,
                                                      const unsigned short* __restrict__ Kp,
                                                      const unsigned short* __restrict__ Vt,
                                                      const float* __restrict__ rel_emb,
                                                      unsigned short* __restrict__ At) {
  __shared__ float bias_s[257];
  __shared__ unsigned short K_lds[2][4096];  // [64 kv][64 d], chunk-swizzled
  __shared__ unsigned short V_lds[2][4096];  // [64 d][64 s], chunk-swizzled
  const int bid0 = blockIdx.x;
  const int lg = (bid0 & 7) * 64 + (bid0 >> 3);  // XCD-bijective remap (512 % 8 == 0)
  const int qb = lg & 15;
  const int h = (lg >> 4) & 7;
  const int b = lg >> 7;
  const int tid = threadIdx.x;
  const int lane = tid & 63, w = tid >> 6;
  const int hi = lane >> 5, q31 = lane & 31;
  const int q0w = qb * 128 + w * 32;
  const int tq = q0w + q31;
  const float SCL = 0.125f * 1.44269504f;

  // ---- staging pointers: 4 per wave, advanced by constant stride per tile ----
  const bool isK = (w < 2);
  const char* sbase = isK ? (const char*)Kp + ((size_t)b * 2048 * 512 + h * 64) * 2
                          : (const char*)Vt + ((size_t)(b * 8 + h) * 64 * 2048) * 2;
  const size_t step = isK ? (size_t)64 * 1024 : 128;  // per-tile advance (bytes)
  const int i0 = (w & 1) * 4;
  // per-ii row/chunk (tile-invariant)
  const int rr0 = (i0 + 0) * 8 + (lane >> 3), ch0 = (lane & 7) ^ (rr0 & 7);
  const int rr1 = (i0 + 1) * 8 + (lane >> 3), ch1 = (lane & 7) ^ (rr1 & 7);
  const int rr2 = (i0 + 2) * 8 + (lane >> 3), ch2 = (lane & 7) ^ (rr2 & 7);
  const int rr3 = (i0 + 3) * 8 + (lane >> 3), ch3 = (lane & 7) ^ (rr3 & 7);
  const size_t rstr = isK ? 1024 : 4096;
  const char* gp0 = sbase + (size_t)rr0 * rstr + ch0 * 16;
  const char* gp1 = sbase + (size_t)rr1 * rstr + ch1 * 16;
  const char* gp2 = sbase + (size_t)rr2 * rstr + ch2 * 16;
  const char* gp3 = sbase + (size_t)rr3 * rstr + ch3 * 16;
  char* db0 = (isK ? (char*)&K_lds[0][0] : (char*)&V_lds[0][0]) + i0 * 4096 / 4;  // i0*1024
  char* db1 = (isK ? (char*)&K_lds[1][0] : (char*)&V_lds[1][0]) + i0 * 1024;

  auto STAGE = [&](char* dbase) {
    gload16(gp0, dbase);
    gload16(gp1, dbase + 1024);
    gload16(gp2, dbase + 2048);
    gload16(gp3, dbase + 3072);
    gp0 += step; gp1 += step; gp2 += step; gp3 += step;
  };

  for (int i = tid; i < 257; i += 256) bias_s[i] = rel_emb[i * 8 + h] * 1.44269504f;
  STAGE(db0);
  __syncthreads();
  const float bias_lo = bias_s[0], bias_hi = bias_s[256];

  const unsigned short* qptr = Qp + (size_t)(b * 2048 + tq) * 512 + h * 64 + hi * 8;
  const bf16x8 qf0 = ld_bf8(qptr);
  const bf16x8 qf1 = ld_bf8(qptr + 16);
  const bf16x8 qf2 = ld_bf8(qptr + 32);
  const bf16x8 qf3 = ld_bf8(qptr + 48);

  // ---- tile-invariant LDS read offsets (elements) ----
  const int rswz = q31 & 7;
  int koff[4], voff[4];
#pragma unroll
  for (int c = 0; c < 4; c++) koff[c] = q31 * 64 + (((2 * c + hi) ^ rswz) << 3);
#pragma unroll
  for (int ks = 0; ks < 4; ks++) voff[ks] = q31 * 64 + (((ks * 2 + hi) ^ rswz) << 3);

  const f32x16 z16 = {0.f, 0.f, 0.f, 0.f, 0.f, 0.f, 0.f, 0.f,
                      0.f, 0.f, 0.f, 0.f, 0.f, 0.f, 0.f, 0.f};
  f32x16 o_lo = z16, o_hi = z16;
  float l_run = 0.f;

  // one tile of r17 math against compile-time-fixed LDS buffers
  auto TILE = [&](const unsigned short* kb, const unsigned short* vb, int s0) {
    f32x16 sa, sb;
    sa = mfma32(ld_bf8(kb + koff[0]), qf0, z16);
    sb = mfma32(ld_bf8(kb + 2048 + koff[0]), qf0, z16);
    sa = mfma32(ld_bf8(kb + koff[1]), qf1, sa);
    sb = mfma32(ld_bf8(kb + 2048 + koff[1]), qf1, sb);
    sa = mfma32(ld_bf8(kb + koff[2]), qf2, sa);
    sb = mfma32(ld_bf8(kb + 2048 + koff[2]), qf2, sb);
    sa = mfma32(ld_bf8(kb + koff[3]), qf3, sa);
    sb = mfma32(ld_bf8(kb + 2048 + koff[3]), qf3, sb);

    bf16x8 vl[4], vh[4];
#pragma unroll
    for (int ks = 0; ks < 4; ks++) {
      vl[ks] = ld_bf8(vb + voff[ks]);
      vh[ks] = ld_bf8(vb + 2048 + voff[ks]);
    }

    const int relmin = q0w - s0 - 63;
    const int relmax = q0w + 31 - s0;
    float SCL2, off0;
    if (relmin >= 128 || relmax <= -128) {
      SCL2 = SCL;
      off0 = (relmin >= 128) ? bias_hi : bias_lo;
    } else {
#pragma unroll
      for (int r = 0; r < 16; r++) {
        const int rowA = (r & 3) + 8 * (r >> 2) + 4 * hi;
        const int rA = tq - s0 - rowA;
        const int rB = rA - 32;
        const int iA = (rA < -128 ? -128 : (rA > 128 ? 128 : rA)) + 128;
        const int iB = (rB < -128 ? -128 : (rB > 128 ? 128 : rB)) + 128;
        sa[r] = fmaf(sa[r], SCL, bias_s[iA]);
        sb[r] = fmaf(sb[r], SCL, bias_s[iB]);
      }
      SCL2 = 1.f;
      off0 = 0.f;
    }

#pragma unroll
    for (int r = 0; r < 16; r++) {
      sa[r] = exp2_fast(fmaf(sa[r], SCL2, off0));
      sb[r] = exp2_fast(fmaf(sb[r], SCL2, off0));
    }
    float s8[8];
#pragma unroll
    for (int i = 0; i < 8; i++)
      s8[i] = (sa[i] + sa[i + 8]) + (sb[i] + sb[i + 8]);
    float ps = ((s8[0] + s8[1]) + (s8[2] + s8[3])) + ((s8[4] + s8[5]) + (s8[6] + s8[7]));
    ps += __shfl_xor(ps, 32, 64);
    l_run += ps;

    bf16x8 pa[4];
#pragma unroll
    for (int ks = 0; ks < 4; ks++) {
      const int c8 = (ks & 1) * 8;
      const f32x16& src = (ks < 2) ? sa : sb;
      unsigned int a0 = cvt_pk_bf16(src[c8 + 0], src[c8 + 1]);
      unsigned int b0 = cvt_pk_bf16(src[c8 + 4], src[c8 + 5]);
      unsigned int a1 = cvt_pk_bf16(src[c8 + 2], src[c8 + 3]);
      unsigned int b1 = cvt_pk_bf16(src[c8 + 6], src[c8 + 7]);
      plane32_swap(a0, b0);
      plane32_swap(a1, b1);
      pa[ks] = __builtin_bit_cast(bf16x8, u32x4{a0, a1, b0, b1});
    }

#pragma unroll
    for (int ks = 0; ks < 4; ks++) {
      o_lo = mfma32(pa[ks], vl[ks], o_lo);
      o_hi = mfma32(pa[ks], vh[ks], o_hi);
    }
  };

  const unsigned short* K0 = &K_lds[0][0];
  const unsigned short* K1 = &K_lds[1][0];
  const unsigned short* V0 = &V_lds[0][0];
  const unsigned short* V1 = &V_lds[1][0];

  for (int t = 0; t < 32; t += 2) {
    STAGE(db1);                 // stage tile t+1 into buf1 (always valid: t+1 <= 31)
    TILE(K0, V0, t * 64);
    __syncthreads();
    if (t + 2 < 32) STAGE(db0); // stage tile t+2 into buf0
    TILE(K1, V1, (t + 1) * 64);
    __syncthreads();
  }

  const float inv = 1.f / l_run;
#pragma unroll
  for (int r2 = 0; r2 < 16; r2++) {
    const int ro = (r2 & 3) + 8 * (r2 >> 2) + 4 * hi;
    const float rr = __shfl(inv, ro, 64);
    unsigned short* op = At + (size_t)(b * 2048 + q0w + ro) * 512 + h * 64;
    op[q31] = f2bf(o_lo[r2] * rr);
    op[32 + q31] = f2bf(o_hi[r2] * rr);
  }
}

// ---------------- host ----------------
extern "C" void kernel_launch(void* const* d_in, const int* in_sizes, int n_in,
                              void* d_out, int out_size, void* d_ws, size_t ws_size,
                              hipStream_t stream) {
  const float* query = (const float*)d_in[0];
  const float* key   = (const float*)d_in[1];
  const float* value = (const float*)d_in[2];
  const float* Wq = (const float*)d_in[3];
  const float* bq = (const float*)d_in[4];
  const float* Wk = (const float*)d_in[5];
  const float* bk = (const float*)d_in[6];
  const float* Wv = (const float*)d_in[7];
  const float* bv = (const float*)d_in[8];
  const float* Wo = (const float*)d_in[9];
  const float* bo = (const float*)d_in[10];
  const float* rel = (const float*)d_in[11];

  char* ws = (char*)d_ws;
  unsigned short* base = (unsigned short*)ws;       // xq xk xv | wq wk wv wo | ...
  unsigned short* wo = base + 3 * SZX_E + 3 * SZW_E;
  unsigned short* Qp = base + 3 * SZX_E + 4 * SZW_E;
  unsigned short* Kp = Qp + SZX_E;
  unsigned short* Vt = Kp + SZX_E;
  unsigned short* At = Vt + SZX_E;

  cvt_all<<<dim3(13312), dim3(256), 0, stream>>>(query, key, value, Wq, Wk, Wv, Wo, base);

  dim3 blk(256);
  gemm_qkv<<<dim3(4, 64, 3), blk, 0, stream>>>(base, bq, bk, bv, Qp);

  attn_kernel<<<dim3(512), blk, 0, stream>>>(Qp, Kp, Vt, rel, At);

  gemm_o<<<dim3(4, 64), blk, 0, stream>>>(At, wo, bo, (float*)d_out);
}

// Round 20
// 102.154 us; speedup vs baseline: 1.1352x; 1.0260x over previous
//
#include <hip/hip_runtime.h>

typedef __attribute__((ext_vector_type(4))) float f32x4;
typedef __attribute__((ext_vector_type(16))) float f32x16;
typedef __attribute__((ext_vector_type(4))) unsigned short u16x4;
typedef __attribute__((ext_vector_type(8))) unsigned short u16x8;
typedef __attribute__((ext_vector_type(4))) unsigned int u32x4;
typedef __attribute__((ext_vector_type(8))) __bf16 bf16x8;

#define SZX_E ((size_t)4 * 2048 * 512)  // elements per activation tensor
#define SZW_E ((size_t)512 * 512)

__device__ __forceinline__ unsigned short f2bf(float f) {
  unsigned int u = __builtin_bit_cast(unsigned int, f);
  u += 0x7fffu + ((u >> 16) & 1u);
  return (unsigned short)(u >> 16);
}

__device__ __forceinline__ bf16x8 ld_bf8(const unsigned short* p) {
  return __builtin_bit_cast(bf16x8, *(const u16x8*)p);
}

__device__ __forceinline__ f32x4 mfma16(bf16x8 a, bf16x8 b, f32x4 c) {
  return __builtin_amdgcn_mfma_f32_16x16x32_bf16(a, b, c, 0, 0, 0);
}

__device__ __forceinline__ f32x16 mfma32(bf16x8 a, bf16x8 b, f32x16 c) {
  return __builtin_amdgcn_mfma_f32_32x32x16_bf16(a, b, c, 0, 0, 0);
}

__device__ __forceinline__ unsigned int cvt_pk_bf16(float lo, float hi) {
  unsigned int r;
  asm("v_cvt_pk_bf16_f32 %0, %1, %2" : "=v"(r) : "v"(lo), "v"(hi));
  return r;
}

__device__ __forceinline__ void plane32_swap(unsigned int& a, unsigned int& b) {
  asm("v_permlane32_swap_b32 %0, %1" : "+v"(a), "+v"(b));
}

// raw v_exp_f32 (2^x); args bounded (|scores*log2e| < ~10) -> equals exp2f.
__device__ __forceinline__ float exp2_fast(float x) {
  float r;
  asm("v_exp_f32 %0, %1" : "=v"(r) : "v"(x));
  return r;
}

// async global->LDS, 16B per lane; LDS dest = WAVE-UNIFORM base, HW adds lane*16
__device__ __forceinline__ void gload16(const void* g, void* l) {
  __builtin_amdgcn_global_load_lds(
      (const __attribute__((address_space(1))) unsigned int*)g,
      (__attribute__((address_space(3))) unsigned int*)l, 16, 0, 0);
}

// ---------------- fused fp32 -> bf16 convert (all 7 tensors, one launch) ----------------
__global__ __launch_bounds__(256) void cvt_all(const float* __restrict__ q_,
                                               const float* __restrict__ k_,
                                               const float* __restrict__ v_,
                                               const float* __restrict__ wq_,
                                               const float* __restrict__ wk_,
                                               const float* __restrict__ wv_,
                                               const float* __restrict__ wo_,
                                               unsigned short* __restrict__ out) {
  const int bq = blockIdx.x;
  const float* src;
  size_t segbase, li;
  if (bq < 12288) {
    const int s = bq >> 12;
    src = (s == 0) ? q_ : (s == 1) ? k_ : v_;
    li = (size_t)(bq & 4095) * 256 + threadIdx.x;
    segbase = (size_t)s * 4194304;
  } else {
    const int s = (bq - 12288) >> 8;
    src = (s == 0) ? wq_ : (s == 1) ? wk_ : (s == 2) ? wv_ : wo_;
    li = (size_t)((bq - 12288) & 255) * 256 + threadIdx.x;
    segbase = 12582912 + (size_t)s * 262144;
  }
  const f32x4 v = *(const f32x4*)(src + li * 4);
  u16x4 r;
  r[0] = f2bf(v[0]); r[1] = f2bf(v[1]); r[2] = f2bf(v[2]); r[3] = f2bf(v[3]);
  *(u16x4*)(out + segbase + li * 4) = r;
}

// ---------------- fused QKV GEMM: z = 0/1/2 -> Q/K/V projection + XCD swizzle ----------------
__global__ __launch_bounds__(256) void gemm_qkv(const unsigned short* __restrict__ base,
                                                const float* __restrict__ bq,
                                                const float* __restrict__ bk,
                                                const float* __restrict__ bv,
                                                unsigned short* __restrict__ outb) {
  __shared__ unsigned short Asb[2][4096];
  __shared__ unsigned short Bsb[2][4096];
  const int z = blockIdx.z;
  const unsigned short* A = base + (size_t)z * SZX_E;
  const unsigned short* Bw = base + 3 * SZX_E + (size_t)z * SZW_E;
  const float* bias = (z == 0) ? bq : (z == 1) ? bk : bv;

  const int tid = threadIdx.x;
  const int l = tid & 63;
  const int w = tid >> 6;
  const int g = l >> 4;
  const int lr = l & 15;
  // T1: cluster 32 consecutive linear ids per XCD so the 4 N-blocks sharing an
  // A-panel (and 8 consecutive A-panels) land on one XCD's L2. 256 % 8 == 0.
  const int bid = blockIdx.x + (blockIdx.y << 2);
  const int lgg = (bid & 7) * 32 + (bid >> 3);
  const int nB = (lgg & 3) * 128;
  const int mB = (lgg >> 2) * 128;
  const int m0 = (w >> 1) * 64;
  const int n0 = (w & 1) * 64;
  const int ubase = tid & ~63;

  auto stage = [&](int bufi, int kk) {
#pragma unroll
    for (int i = 0; i < 2; i++) {
      const int idx = i * 256 + tid;
      const int ub = i * 256 + ubase;
      const int r = idx >> 2, c = idx & 3;
      gload16((const char*)A + ((size_t)(mB + r) * 512 + kk + c * 8) * 2,
              (char*)&Asb[bufi][0] + ub * 16);
      gload16((const char*)Bw + ((size_t)(nB + r) * 512 + kk + c * 8) * 2,
              (char*)&Bsb[bufi][0] + ub * 16);
    }
  };

  f32x4 acc[4][4];
#pragma unroll
  for (int i = 0; i < 4; i++)
#pragma unroll
    for (int j = 0; j < 4; j++) acc[i][j] = f32x4{0.f, 0.f, 0.f, 0.f};

  stage(0, 0);
  __syncthreads();
  int buf = 0;

  for (int ks = 0; ks < 16; ++ks) {
    if (ks < 15) stage(buf ^ 1, (ks + 1) * 32);
    bf16x8 af[4], bfr[4];
#pragma unroll
    for (int t = 0; t < 4; t++) {
      af[t] = ld_bf8(&Asb[buf][(m0 + t * 16 + lr) * 32 + g * 8]);
      bfr[t] = ld_bf8(&Bsb[buf][(n0 + t * 16 + lr) * 32 + g * 8]);
    }
#pragma unroll
    for (int i = 0; i < 4; i++)
#pragma unroll
      for (int j = 0; j < 4; j++)
        acc[i][j] = mfma16(af[i], bfr[j], acc[i][j]);
    __syncthreads();
    buf ^= 1;
  }

  unsigned short* outz = outb + (size_t)z * SZX_E;  // Qp / Kp / Vt
#pragma unroll
  for (int j = 0; j < 4; j++) {
    const int n = nB + n0 + j * 16 + lr;
    const float bn = bias[n];
#pragma unroll
    for (int i = 0; i < 4; i++) {
#pragma unroll
      for (int r = 0; r < 4; r++) {
        const int m = mB + m0 + i * 16 + g * 4 + r;
        const float v = acc[i][j][r] + bn;
        if (z < 2) {
          outz[(size_t)m * 512 + n] = f2bf(v);
        } else {
          const int bb = m >> 11, s = m & 2047;
          const int hh = n >> 6, d = n & 63;
          outz[((size_t)((bb * 8 + hh) * 64 + d) << 11) + s] = f2bf(v);
        }
      }
    }
  }
}

// ---------------- output GEMM: fp32 out + bias + XCD swizzle ----------------
__global__ __launch_bounds__(256) void gemm_o(const unsigned short* __restrict__ A,
                                              const unsigned short* __restrict__ Bw,
                                              const float* __restrict__ bias,
                                              float* __restrict__ Cout) {
  __shared__ unsigned short Asb[2][4096];
  __shared__ unsigned short Bsb[2][4096];
  const int tid = threadIdx.x;
  const int l = tid & 63;
  const int w = tid >> 6;
  const int g = l >> 4;
  const int lr = l & 15;
  const int bid = blockIdx.x + (blockIdx.y << 2);
  const int lgg = (bid & 7) * 32 + (bid >> 3);
  const int nB = (lgg & 3) * 128;
  const int mB = (lgg >> 2) * 128;
  const int m0 = (w >> 1) * 64;
  const int n0 = (w & 1) * 64;
  const int ubase = tid & ~63;

  auto stage = [&](int bufi, int kk) {
#pragma unroll
    for (int i = 0; i < 2; i++) {
      const int idx = i * 256 + tid;
      const int ub = i * 256 + ubase;
      const int r = idx >> 2, c = idx & 3;
      gload16((const char*)A + ((size_t)(mB + r) * 512 + kk + c * 8) * 2,
              (char*)&Asb[bufi][0] + ub * 16);
      gload16((const char*)Bw + ((size_t)(nB + r) * 512 + kk + c * 8) * 2,
              (char*)&Bsb[bufi][0] + ub * 16);
    }
  };

  f32x4 acc[4][4];
#pragma unroll
  for (int i = 0; i < 4; i++)
#pragma unroll
    for (int j = 0; j < 4; j++) acc[i][j] = f32x4{0.f, 0.f, 0.f, 0.f};

  stage(0, 0);
  __syncthreads();
  int buf = 0;

  for (int ks = 0; ks < 16; ++ks) {
    if (ks < 15) stage(buf ^ 1, (ks + 1) * 32);
    bf16x8 af[4], bfr[4];
#pragma unroll
    for (int t = 0; t < 4; t++) {
      af[t] = ld_bf8(&Asb[buf][(m0 + t * 16 + lr) * 32 + g * 8]);
      bfr[t] = ld_bf8(&Bsb[buf][(n0 + t * 16 + lr) * 32 + g * 8]);
    }
#pragma unroll
    for (int i = 0; i < 4; i++)
#pragma unroll
      for (int j = 0; j < 4; j++)
        acc[i][j] = mfma16(af[i], bfr[j], acc[i][j]);
    __syncthreads();
    buf ^= 1;
  }

#pragma unroll
  for (int j = 0; j < 4; j++) {
    const int n = nB + n0 + j * 16 + lr;
    const float bn = bias[n];
#pragma unroll
    for (int i = 0; i < 4; i++) {
#pragma unroll
      for (int r = 0; r < 4; r++) {
        const int m = mB + m0 + i * 16 + g * 4 + r;
        Cout[(size_t)m * 512 + n] = acc[i][j][r] + bn;
      }
    }
  }
}

// ---------------- flash attention: r19 + explicit K/V load block before MFMA chain ----------------
// LDS returns are FIFO: K-reads issue first, V-reads queue behind; the QK^T MFMAs
// wait only on the K returns (fine lgkmcnt) while V latency hides under the chain.
__global__ __launch_bounds__(256, 2) void attn_kernel(const unsigned short* __restrict__ Qp,
                                                      const unsigned short* __restrict__ Kp,
                                                      const unsigned short* __restrict__ Vt,
                                                      const float* __restrict__ rel_emb,
                                                      unsigned short* __restrict__ At) {
  __shared__ float bias_s[257];
  __shared__ unsigned short K_lds[2][4096];  // [64 kv][64 d], chunk-swizzled
  __shared__ unsigned short V_lds[2][4096];  // [64 d][64 s], chunk-swizzled
  const int bid0 = blockIdx.x;
  const int lg = (bid0 & 7) * 64 + (bid0 >> 3);  // XCD-bijective remap (512 % 8 == 0)
  const int qb = lg & 15;
  const int h = (lg >> 4) & 7;
  const int b = lg >> 7;
  const int tid = threadIdx.x;
  const int lane = tid & 63, w = tid >> 6;
  const int hi = lane >> 5, q31 = lane & 31;
  const int q0w = qb * 128 + w * 32;
  const int tq = q0w + q31;
  const float SCL = 0.125f * 1.44269504f;

  const bool isK = (w < 2);
  const char* sbase = isK ? (const char*)Kp + ((size_t)b * 2048 * 512 + h * 64) * 2
                          : (const char*)Vt + ((size_t)(b * 8 + h) * 64 * 2048) * 2;
  const size_t step = isK ? (size_t)64 * 1024 : 128;
  const int i0 = (w & 1) * 4;
  const int rr0 = (i0 + 0) * 8 + (lane >> 3), ch0 = (lane & 7) ^ (rr0 & 7);
  const int rr1 = (i0 + 1) * 8 + (lane >> 3), ch1 = (lane & 7) ^ (rr1 & 7);
  const int rr2 = (i0 + 2) * 8 + (lane >> 3), ch2 = (lane & 7) ^ (rr2 & 7);
  const int rr3 = (i0 + 3) * 8 + (lane >> 3), ch3 = (lane & 7) ^ (rr3 & 7);
  const size_t rstr = isK ? 1024 : 4096;
  const char* gp0 = sbase + (size_t)rr0 * rstr + ch0 * 16;
  const char* gp1 = sbase + (size_t)rr1 * rstr + ch1 * 16;
  const char* gp2 = sbase + (size_t)rr2 * rstr + ch2 * 16;
  const char* gp3 = sbase + (size_t)rr3 * rstr + ch3 * 16;
  char* db0 = (isK ? (char*)&K_lds[0][0] : (char*)&V_lds[0][0]) + i0 * 1024;
  char* db1 = (isK ? (char*)&K_lds[1][0] : (char*)&V_lds[1][0]) + i0 * 1024;

  auto STAGE = [&](char* dbase) {
    gload16(gp0, dbase);
    gload16(gp1, dbase + 1024);
    gload16(gp2, dbase + 2048);
    gload16(gp3, dbase + 3072);
    gp0 += step; gp1 += step; gp2 += step; gp3 += step;
  };

  for (int i = tid; i < 257; i += 256) bias_s[i] = rel_emb[i * 8 + h] * 1.44269504f;
  STAGE(db0);
  __syncthreads();
  const float bias_lo = bias_s[0], bias_hi = bias_s[256];

  const unsigned short* qptr = Qp + (size_t)(b * 2048 + tq) * 512 + h * 64 + hi * 8;
  const bf16x8 qf0 = ld_bf8(qptr);
  const bf16x8 qf1 = ld_bf8(qptr + 16);
  const bf16x8 qf2 = ld_bf8(qptr + 32);
  const bf16x8 qf3 = ld_bf8(qptr + 48);

  const int rswz = q31 & 7;
  int koff[4], voff[4];
#pragma unroll
  for (int c = 0; c < 4; c++) koff[c] = q31 * 64 + (((2 * c + hi) ^ rswz) << 3);
#pragma unroll
  for (int ks = 0; ks < 4; ks++) voff[ks] = q31 * 64 + (((ks * 2 + hi) ^ rswz) << 3);

  const f32x16 z16 = {0.f, 0.f, 0.f, 0.f, 0.f, 0.f, 0.f, 0.f,
                      0.f, 0.f, 0.f, 0.f, 0.f, 0.f, 0.f, 0.f};
  f32x16 o_lo = z16, o_hi = z16;
  float l_run = 0.f;

  auto TILE = [&](const unsigned short* kb, const unsigned short* vb, int s0) {
    // explicit load block: K reads first (MFMAs wait only on these), V reads queued behind
    bf16x8 kfl0 = ld_bf8(kb + koff[0]);
    bf16x8 kfh0 = ld_bf8(kb + 2048 + koff[0]);
    bf16x8 kfl1 = ld_bf8(kb + koff[1]);
    bf16x8 kfh1 = ld_bf8(kb + 2048 + koff[1]);
    bf16x8 kfl2 = ld_bf8(kb + koff[2]);
    bf16x8 kfh2 = ld_bf8(kb + 2048 + koff[2]);
    bf16x8 kfl3 = ld_bf8(kb + koff[3]);
    bf16x8 kfh3 = ld_bf8(kb + 2048 + koff[3]);
    bf16x8 vl[4], vh[4];
#pragma unroll
    for (int ks = 0; ks < 4; ks++) {
      vl[ks] = ld_bf8(vb + voff[ks]);
      vh[ks] = ld_bf8(vb + 2048 + voff[ks]);
    }

    f32x16 sa, sb;
    sa = mfma32(kfl0, qf0, z16);
    sb = mfma32(kfh0, qf0, z16);
    sa = mfma32(kfl1, qf1, sa);
    sb = mfma32(kfh1, qf1, sb);
    sa = mfma32(kfl2, qf2, sa);
    sb = mfma32(kfh2, qf2, sb);
    sa = mfma32(kfl3, qf3, sa);
    sb = mfma32(kfh3, qf3, sb);

    const int relmin = q0w - s0 - 63;
    const int relmax = q0w + 31 - s0;
    float SCL2, off0;
    if (relmin >= 128 || relmax <= -128) {
      SCL2 = SCL;
      off0 = (relmin >= 128) ? bias_hi : bias_lo;
    } else {
#pragma unroll
      for (int r = 0; r < 16; r++) {
        const int rowA = (r & 3) + 8 * (r >> 2) + 4 * hi;
        const int rA = tq - s0 - rowA;
        const int rB = rA - 32;
        const int iA = (rA < -128 ? -128 : (rA > 128 ? 128 : rA)) + 128;
        const int iB = (rB < -128 ? -128 : (rB > 128 ? 128 : rB)) + 128;
        sa[r] = fmaf(sa[r], SCL, bias_s[iA]);
        sb[r] = fmaf(sb[r], SCL, bias_s[iB]);
      }
      SCL2 = 1.f;
      off0 = 0.f;
    }

#pragma unroll
    for (int r = 0; r < 16; r++) {
      sa[r] = exp2_fast(fmaf(sa[r], SCL2, off0));
      sb[r] = exp2_fast(fmaf(sb[r], SCL2, off0));
    }
    float s8[8];
#pragma unroll
    for (int i = 0; i < 8; i++)
      s8[i] = (sa[i] + sa[i + 8]) + (sb[i] + sb[i + 8]);
    float ps = ((s8[0] + s8[1]) + (s8[2] + s8[3])) + ((s8[4] + s8[5]) + (s8[6] + s8[7]));
    ps += __shfl_xor(ps, 32, 64);
    l_run += ps;

    bf16x8 pa[4];
#pragma unroll
    for (int ks = 0; ks < 4; ks++) {
      const int c8 = (ks & 1) * 8;
      const f32x16& src = (ks < 2) ? sa : sb;
      unsigned int a0 = cvt_pk_bf16(src[c8 + 0], src[c8 + 1]);
      unsigned int b0 = cvt_pk_bf16(src[c8 + 4], src[c8 + 5]);
      unsigned int a1 = cvt_pk_bf16(src[c8 + 2], src[c8 + 3]);
      unsigned int b1 = cvt_pk_bf16(src[c8 + 6], src[c8 + 7]);
      plane32_swap(a0, b0);
      plane32_swap(a1, b1);
      pa[ks] = __builtin_bit_cast(bf16x8, u32x4{a0, a1, b0, b1});
    }

#pragma unroll
    for (int ks = 0; ks < 4; ks++) {
      o_lo = mfma32(pa[ks], vl[ks], o_lo);
      o_hi = mfma32(pa[ks], vh[ks], o_hi);
    }
  };

  const unsigned short* K0 = &K_lds[0][0];
  const unsigned short* K1 = &K_lds[1][0];
  const unsigned short* V0 = &V_lds[0][0];
  const unsigned short* V1 = &V_lds[1][0];

  for (int t = 0; t < 32; t += 2) {
    STAGE(db1);
    TILE(K0, V0, t * 64);
    __syncthreads();
    if (t + 2 < 32) STAGE(db0);
    TILE(K1, V1, (t + 1) * 64);
    __syncthreads();
  }

  const float inv = 1.f / l_run;
#pragma unroll
  for (int r2 = 0; r2 < 16; r2++) {
    const int ro = (r2 & 3) + 8 * (r2 >> 2) + 4 * hi;
    const float rr = __shfl(inv, ro, 64);
    unsigned short* op = At + (size_t)(b * 2048 + q0w + ro) * 512 + h * 64;
    op[q31] = f2bf(o_lo[r2] * rr);
    op[32 + q31] = f2bf(o_hi[r2] * rr);
  }
}

// ---------------- host ----------------
extern "C" void kernel_launch(void* const* d_in, const int* in_sizes, int n_in,
                              void* d_out, int out_size, void* d_ws, size_t ws_size,
                              hipStream_t stream) {
  const float* query = (const float*)d_in[0];
  const float* key   = (const float*)d_in[1];
  const float* value = (const float*)d_in[2];
  const float* Wq = (const float*)d_in[3];
  const float* bq = (const float*)d_in[4];
  const float* Wk = (const float*)d_in[5];
  const float* bk = (const float*)d_in[6];
  const float* Wv = (const float*)d_in[7];
  const float* bv = (const float*)d_in[8];
  const float* Wo = (const float*)d_in[9];
  const float* bo = (const float*)d_in[10];
  const float* rel = (const float*)d_in[11];

  char* ws = (char*)d_ws;
  unsigned short* base = (unsigned short*)ws;       // xq xk xv | wq wk wv wo | ...
  unsigned short* wo = base + 3 * SZX_E + 3 * SZW_E;
  unsigned short* Qp = base + 3 * SZX_E + 4 * SZW_E;
  unsigned short* Kp = Qp + SZX_E;
  unsigned short* Vt = Kp + SZX_E;
  unsigned short* At = Vt + SZX_E;

  cvt_all<<<dim3(13312), dim3(256), 0, stream>>>(query, key, value, Wq, Wk, Wv, Wo, base);

  dim3 blk(256);
  gemm_qkv<<<dim3(4, 64, 3), blk, 0, stream>>>(base, bq, bk, bv, Qp);

  attn_kernel<<<dim3(512), blk, 0, stream>>>(Qp, Kp, Vt, rel, At);

  gemm_o<<<dim3(4, 64), blk, 0, stream>>>(At, wo, bo, (float*)d_out);
}

// Round 21
// 101.922 us; speedup vs baseline: 1.1378x; 1.0023x over previous
//
#include <hip/hip_runtime.h>

typedef __attribute__((ext_vector_type(4))) float f32x4;
typedef __attribute__((ext_vector_type(16))) float f32x16;
typedef __attribute__((ext_vector_type(4))) unsigned short u16x4;
typedef __attribute__((ext_vector_type(8))) unsigned short u16x8;
typedef __attribute__((ext_vector_type(4))) unsigned int u32x4;
typedef __attribute__((ext_vector_type(8))) __bf16 bf16x8;

#define SZX_E ((size_t)4 * 2048 * 512)  // elements per activation tensor
#define SZW_E ((size_t)512 * 512)

__device__ __forceinline__ unsigned short f2bf(float f) {
  unsigned int u = __builtin_bit_cast(unsigned int, f);
  u += 0x7fffu + ((u >> 16) & 1u);
  return (unsigned short)(u >> 16);
}

__device__ __forceinline__ bf16x8 ld_bf8(const unsigned short* p) {
  return __builtin_bit_cast(bf16x8, *(const u16x8*)p);
}

__device__ __forceinline__ f32x4 mfma16(bf16x8 a, bf16x8 b, f32x4 c) {
  return __builtin_amdgcn_mfma_f32_16x16x32_bf16(a, b, c, 0, 0, 0);
}

__device__ __forceinline__ f32x16 mfma32(bf16x8 a, bf16x8 b, f32x16 c) {
  return __builtin_amdgcn_mfma_f32_32x32x16_bf16(a, b, c, 0, 0, 0);
}

__device__ __forceinline__ unsigned int cvt_pk_bf16(float lo, float hi) {
  unsigned int r;
  asm("v_cvt_pk_bf16_f32 %0, %1, %2" : "=v"(r) : "v"(lo), "v"(hi));
  return r;
}

__device__ __forceinline__ void plane32_swap(unsigned int& a, unsigned int& b) {
  asm("v_permlane32_swap_b32 %0, %1" : "+v"(a), "+v"(b));
}

// raw v_exp_f32 (2^x); args bounded (|scores*log2e| < ~10) -> equals exp2f.
__device__ __forceinline__ float exp2_fast(float x) {
  float r;
  asm("v_exp_f32 %0, %1" : "=v"(r) : "v"(x));
  return r;
}

// async global->LDS, 16B per lane; LDS dest = WAVE-UNIFORM base, HW adds lane*16
__device__ __forceinline__ void gload16(const void* g, void* l) {
  __builtin_amdgcn_global_load_lds(
      (const __attribute__((address_space(1))) unsigned int*)g,
      (__attribute__((address_space(3))) unsigned int*)l, 16, 0, 0);
}

// counted-vmcnt barrier (T4): my own previous-tile staging loads done, then block barrier.
// sched_barrier fences prevent hoisting (rule #18).
#define VBAR4 do { \
    asm volatile("s_waitcnt vmcnt(4)" ::: "memory"); \
    __builtin_amdgcn_sched_barrier(0); \
    __builtin_amdgcn_s_barrier(); \
    __builtin_amdgcn_sched_barrier(0); \
  } while (0)
#define VBAR0 do { \
    asm volatile("s_waitcnt vmcnt(0)" ::: "memory"); \
    __builtin_amdgcn_sched_barrier(0); \
    __builtin_amdgcn_s_barrier(); \
    __builtin_amdgcn_sched_barrier(0); \
  } while (0)

// ---------------- fused fp32 -> bf16 convert (all 7 tensors, one launch) ----------------
__global__ __launch_bounds__(256) void cvt_all(const float* __restrict__ q_,
                                               const float* __restrict__ k_,
                                               const float* __restrict__ v_,
                                               const float* __restrict__ wq_,
                                               const float* __restrict__ wk_,
                                               const float* __restrict__ wv_,
                                               const float* __restrict__ wo_,
                                               unsigned short* __restrict__ out) {
  const int bq = blockIdx.x;
  const float* src;
  size_t segbase, li;
  if (bq < 12288) {
    const int s = bq >> 12;
    src = (s == 0) ? q_ : (s == 1) ? k_ : v_;
    li = (size_t)(bq & 4095) * 256 + threadIdx.x;
    segbase = (size_t)s * 4194304;
  } else {
    const int s = (bq - 12288) >> 8;
    src = (s == 0) ? wq_ : (s == 1) ? wk_ : (s == 2) ? wv_ : wo_;
    li = (size_t)((bq - 12288) & 255) * 256 + threadIdx.x;
    segbase = 12582912 + (size_t)s * 262144;
  }
  const f32x4 v = *(const f32x4*)(src + li * 4);
  u16x4 r;
  r[0] = f2bf(v[0]); r[1] = f2bf(v[1]); r[2] = f2bf(v[2]); r[3] = f2bf(v[3]);
  *(u16x4*)(out + segbase + li * 4) = r;
}

// ---------------- fused QKV GEMM: z = 0/1/2 -> Q/K/V projection + XCD swizzle ----------------
__global__ __launch_bounds__(256) void gemm_qkv(const unsigned short* __restrict__ base,
                                                const float* __restrict__ bq,
                                                const float* __restrict__ bk,
                                                const float* __restrict__ bv,
                                                unsigned short* __restrict__ outb) {
  __shared__ unsigned short Asb[2][4096];
  __shared__ unsigned short Bsb[2][4096];
  const int z = blockIdx.z;
  const unsigned short* A = base + (size_t)z * SZX_E;
  const unsigned short* Bw = base + 3 * SZX_E + (size_t)z * SZW_E;
  const float* bias = (z == 0) ? bq : (z == 1) ? bk : bv;

  const int tid = threadIdx.x;
  const int l = tid & 63;
  const int w = tid >> 6;
  const int g = l >> 4;
  const int lr = l & 15;
  const int bid = blockIdx.x + (blockIdx.y << 2);
  const int lgg = (bid & 7) * 32 + (bid >> 3);
  const int nB = (lgg & 3) * 128;
  const int mB = (lgg >> 2) * 128;
  const int m0 = (w >> 1) * 64;
  const int n0 = (w & 1) * 64;
  const int ubase = tid & ~63;

  auto stage = [&](int bufi, int kk) {
#pragma unroll
    for (int i = 0; i < 2; i++) {
      const int idx = i * 256 + tid;
      const int ub = i * 256 + ubase;
      const int r = idx >> 2, c = idx & 3;
      gload16((const char*)A + ((size_t)(mB + r) * 512 + kk + c * 8) * 2,
              (char*)&Asb[bufi][0] + ub * 16);
      gload16((const char*)Bw + ((size_t)(nB + r) * 512 + kk + c * 8) * 2,
              (char*)&Bsb[bufi][0] + ub * 16);
    }
  };

  f32x4 acc[4][4];
#pragma unroll
  for (int i = 0; i < 4; i++)
#pragma unroll
    for (int j = 0; j < 4; j++) acc[i][j] = f32x4{0.f, 0.f, 0.f, 0.f};

  stage(0, 0);
  __syncthreads();
  int buf = 0;

  for (int ks = 0; ks < 16; ++ks) {
    if (ks < 15) stage(buf ^ 1, (ks + 1) * 32);
    bf16x8 af[4], bfr[4];
#pragma unroll
    for (int t = 0; t < 4; t++) {
      af[t] = ld_bf8(&Asb[buf][(m0 + t * 16 + lr) * 32 + g * 8]);
      bfr[t] = ld_bf8(&Bsb[buf][(n0 + t * 16 + lr) * 32 + g * 8]);
    }
#pragma unroll
    for (int i = 0; i < 4; i++)
#pragma unroll
      for (int j = 0; j < 4; j++)
        acc[i][j] = mfma16(af[i], bfr[j], acc[i][j]);
    __syncthreads();
    buf ^= 1;
  }

  unsigned short* outz = outb + (size_t)z * SZX_E;  // Qp / Kp / Vt
#pragma unroll
  for (int j = 0; j < 4; j++) {
    const int n = nB + n0 + j * 16 + lr;
    const float bn = bias[n];
#pragma unroll
    for (int i = 0; i < 4; i++) {
#pragma unroll
      for (int r = 0; r < 4; r++) {
        const int m = mB + m0 + i * 16 + g * 4 + r;
        const float v = acc[i][j][r] + bn;
        if (z < 2) {
          outz[(size_t)m * 512 + n] = f2bf(v);
        } else {
          const int bb = m >> 11, s = m & 2047;
          const int hh = n >> 6, d = n & 63;
          outz[((size_t)((bb * 8 + hh) * 64 + d) << 11) + s] = f2bf(v);
        }
      }
    }
  }
}

// ---------------- output GEMM: fp32 out + bias + XCD swizzle ----------------
__global__ __launch_bounds__(256) void gemm_o(const unsigned short* __restrict__ A,
                                              const unsigned short* __restrict__ Bw,
                                              const float* __restrict__ bias,
                                              float* __restrict__ Cout) {
  __shared__ unsigned short Asb[2][4096];
  __shared__ unsigned short Bsb[2][4096];
  const int tid = threadIdx.x;
  const int l = tid & 63;
  const int w = tid >> 6;
  const int g = l >> 4;
  const int lr = l & 15;
  const int bid = blockIdx.x + (blockIdx.y << 2);
  const int lgg = (bid & 7) * 32 + (bid >> 3);
  const int nB = (lgg & 3) * 128;
  const int mB = (lgg >> 2) * 128;
  const int m0 = (w >> 1) * 64;
  const int n0 = (w & 1) * 64;
  const int ubase = tid & ~63;

  auto stage = [&](int bufi, int kk) {
#pragma unroll
    for (int i = 0; i < 2; i++) {
      const int idx = i * 256 + tid;
      const int ub = i * 256 + ubase;
      const int r = idx >> 2, c = idx & 3;
      gload16((const char*)A + ((size_t)(mB + r) * 512 + kk + c * 8) * 2,
              (char*)&Asb[bufi][0] + ub * 16);
      gload16((const char*)Bw + ((size_t)(nB + r) * 512 + kk + c * 8) * 2,
              (char*)&Bsb[bufi][0] + ub * 16);
    }
  };

  f32x4 acc[4][4];
#pragma unroll
  for (int i = 0; i < 4; i++)
#pragma unroll
    for (int j = 0; j < 4; j++) acc[i][j] = f32x4{0.f, 0.f, 0.f, 0.f};

  stage(0, 0);
  __syncthreads();
  int buf = 0;

  for (int ks = 0; ks < 16; ++ks) {
    if (ks < 15) stage(buf ^ 1, (ks + 1) * 32);
    bf16x8 af[4], bfr[4];
#pragma unroll
    for (int t = 0; t < 4; t++) {
      af[t] = ld_bf8(&Asb[buf][(m0 + t * 16 + lr) * 32 + g * 8]);
      bfr[t] = ld_bf8(&Bsb[buf][(n0 + t * 16 + lr) * 32 + g * 8]);
    }
#pragma unroll
    for (int i = 0; i < 4; i++)
#pragma unroll
      for (int j = 0; j < 4; j++)
        acc[i][j] = mfma16(af[i], bfr[j], acc[i][j]);
    __syncthreads();
    buf ^= 1;
  }

#pragma unroll
  for (int j = 0; j < 4; j++) {
    const int n = nB + n0 + j * 16 + lr;
    const float bn = bias[n];
#pragma unroll
    for (int i = 0; i < 4; i++) {
#pragma unroll
      for (int r = 0; r < 4; r++) {
        const int m = mB + m0 + i * 16 + g * 4 + r;
        Cout[(size_t)m * 512 + n] = acc[i][j][r] + bn;
      }
    }
  }
}

// ---------------- flash attention: triple-buffer + counted vmcnt (T4) ----------------
// r20 math/layout; per-tile __syncthreads (vmcnt(0) drain) replaced by
// s_waitcnt vmcnt(4) + raw s_barrier over 3 LDS buffers -> staging loads span barriers.
__global__ __launch_bounds__(256, 2) void attn_kernel(const unsigned short* __restrict__ Qp,
                                                      const unsigned short* __restrict__ Kp,
                                                      const unsigned short* __restrict__ Vt,
                                                      const float* __restrict__ rel_emb,
                                                      unsigned short* __restrict__ At) {
  __shared__ float bias_s[257];
  __shared__ unsigned short K_lds[3][4096];  // [64 kv][64 d], chunk-swizzled
  __shared__ unsigned short V_lds[3][4096];  // [64 d][64 s], chunk-swizzled
  const int bid0 = blockIdx.x;
  const int lg = (bid0 & 7) * 64 + (bid0 >> 3);  // XCD-bijective remap (512 % 8 == 0)
  const int qb = lg & 15;
  const int h = (lg >> 4) & 7;
  const int b = lg >> 7;
  const int tid = threadIdx.x;
  const int lane = tid & 63, w = tid >> 6;
  const int hi = lane >> 5, q31 = lane & 31;
  const int q0w = qb * 128 + w * 32;
  const int tq = q0w + q31;
  const float SCL = 0.125f * 1.44269504f;

  const bool isK = (w < 2);
  const char* sbase = isK ? (const char*)Kp + ((size_t)b * 2048 * 512 + h * 64) * 2
                          : (const char*)Vt + ((size_t)(b * 8 + h) * 64 * 2048) * 2;
  const size_t step = isK ? (size_t)64 * 1024 : 128;
  const int i0 = (w & 1) * 4;
  const int rr0 = (i0 + 0) * 8 + (lane >> 3), ch0 = (lane & 7) ^ (rr0 & 7);
  const int rr1 = (i0 + 1) * 8 + (lane >> 3), ch1 = (lane & 7) ^ (rr1 & 7);
  const int rr2 = (i0 + 2) * 8 + (lane >> 3), ch2 = (lane & 7) ^ (rr2 & 7);
  const int rr3 = (i0 + 3) * 8 + (lane >> 3), ch3 = (lane & 7) ^ (rr3 & 7);
  const size_t rstr = isK ? 1024 : 4096;
  const char* gp0 = sbase + (size_t)rr0 * rstr + ch0 * 16;
  const char* gp1 = sbase + (size_t)rr1 * rstr + ch1 * 16;
  const char* gp2 = sbase + (size_t)rr2 * rstr + ch2 * 16;
  const char* gp3 = sbase + (size_t)rr3 * rstr + ch3 * 16;
  char* dbA = (isK ? (char*)&K_lds[0][0] : (char*)&V_lds[0][0]) + i0 * 1024;
  char* dbB = (isK ? (char*)&K_lds[1][0] : (char*)&V_lds[1][0]) + i0 * 1024;
  char* dbC = (isK ? (char*)&K_lds[2][0] : (char*)&V_lds[2][0]) + i0 * 1024;

  auto STAGE = [&](char* dbase) {
    gload16(gp0, dbase);
    gload16(gp1, dbase + 1024);
    gload16(gp2, dbase + 2048);
    gload16(gp3, dbase + 3072);
    gp0 += step; gp1 += step; gp2 += step; gp3 += step;
  };

  // Q loads first (FIFO head; drained by the prologue __syncthreads)
  const unsigned short* qptr = Qp + (size_t)(b * 2048 + tq) * 512 + h * 64 + hi * 8;
  const bf16x8 qf0 = ld_bf8(qptr);
  const bf16x8 qf1 = ld_bf8(qptr + 16);
  const bf16x8 qf2 = ld_bf8(qptr + 32);
  const bf16x8 qf3 = ld_bf8(qptr + 48);

  STAGE(dbA);  // tile 0
  STAGE(dbB);  // tile 1
  for (int i = tid; i < 257; i += 256) bias_s[i] = rel_emb[i * 8 + h] * 1.44269504f;
  __syncthreads();  // one-time full drain (bias + prologue stages + Q)
  const float bias_lo = bias_s[0], bias_hi = bias_s[256];

  const int rswz = q31 & 7;
  int koff[4], voff[4];
#pragma unroll
  for (int c = 0; c < 4; c++) koff[c] = q31 * 64 + (((2 * c + hi) ^ rswz) << 3);
#pragma unroll
  for (int ks = 0; ks < 4; ks++) voff[ks] = q31 * 64 + (((ks * 2 + hi) ^ rswz) << 3);

  const f32x16 z16 = {0.f, 0.f, 0.f, 0.f, 0.f, 0.f, 0.f, 0.f,
                      0.f, 0.f, 0.f, 0.f, 0.f, 0.f, 0.f, 0.f};
  f32x16 o_lo = z16, o_hi = z16;
  float l_run = 0.f;

  auto TILE = [&](const unsigned short* kb, const unsigned short* vb, int s0) {
    bf16x8 kfl0 = ld_bf8(kb + koff[0]);
    bf16x8 kfh0 = ld_bf8(kb + 2048 + koff[0]);
    bf16x8 kfl1 = ld_bf8(kb + koff[1]);
    bf16x8 kfh1 = ld_bf8(kb + 2048 + koff[1]);
    bf16x8 kfl2 = ld_bf8(kb + koff[2]);
    bf16x8 kfh2 = ld_bf8(kb + 2048 + koff[2]);
    bf16x8 kfl3 = ld_bf8(kb + koff[3]);
    bf16x8 kfh3 = ld_bf8(kb + 2048 + koff[3]);
    bf16x8 vl[4], vh[4];
#pragma unroll
    for (int ks = 0; ks < 4; ks++) {
      vl[ks] = ld_bf8(vb + voff[ks]);
      vh[ks] = ld_bf8(vb + 2048 + voff[ks]);
    }

    f32x16 sa, sb;
    sa = mfma32(kfl0, qf0, z16);
    sb = mfma32(kfh0, qf0, z16);
    sa = mfma32(kfl1, qf1, sa);
    sb = mfma32(kfh1, qf1, sb);
    sa = mfma32(kfl2, qf2, sa);
    sb = mfma32(kfh2, qf2, sb);
    sa = mfma32(kfl3, qf3, sa);
    sb = mfma32(kfh3, qf3, sb);

    const int relmin = q0w - s0 - 63;
    const int relmax = q0w + 31 - s0;
    float SCL2, off0;
    if (relmin >= 128 || relmax <= -128) {
      SCL2 = SCL;
      off0 = (relmin >= 128) ? bias_hi : bias_lo;
    } else {
#pragma unroll
      for (int r = 0; r < 16; r++) {
        const int rowA = (r & 3) + 8 * (r >> 2) + 4 * hi;
        const int rA = tq - s0 - rowA;
        const int rB = rA - 32;
        const int iA = (rA < -128 ? -128 : (rA > 128 ? 128 : rA)) + 128;
        const int iB = (rB < -128 ? -128 : (rB > 128 ? 128 : rB)) + 128;
        sa[r] = fmaf(sa[r], SCL, bias_s[iA]);
        sb[r] = fmaf(sb[r], SCL, bias_s[iB]);
      }
      SCL2 = 1.f;
      off0 = 0.f;
    }

#pragma unroll
    for (int r = 0; r < 16; r++) {
      sa[r] = exp2_fast(fmaf(sa[r], SCL2, off0));
      sb[r] = exp2_fast(fmaf(sb[r], SCL2, off0));
    }
    float s8[8];
#pragma unroll
    for (int i = 0; i < 8; i++)
      s8[i] = (sa[i] + sa[i + 8]) + (sb[i] + sb[i + 8]);
    float ps = ((s8[0] + s8[1]) + (s8[2] + s8[3])) + ((s8[4] + s8[5]) + (s8[6] + s8[7]));
    ps += __shfl_xor(ps, 32, 64);
    l_run += ps;

    bf16x8 pa[4];
#pragma unroll
    for (int ks = 0; ks < 4; ks++) {
      const int c8 = (ks & 1) * 8;
      const f32x16& src = (ks < 2) ? sa : sb;
      unsigned int a0 = cvt_pk_bf16(src[c8 + 0], src[c8 + 1]);
      unsigned int b0 = cvt_pk_bf16(src[c8 + 4], src[c8 + 5]);
      unsigned int a1 = cvt_pk_bf16(src[c8 + 2], src[c8 + 3]);
      unsigned int b1 = cvt_pk_bf16(src[c8 + 6], src[c8 + 7]);
      plane32_swap(a0, b0);
      plane32_swap(a1, b1);
      pa[ks] = __builtin_bit_cast(bf16x8, u32x4{a0, a1, b0, b1});
    }

#pragma unroll
    for (int ks = 0; ks < 4; ks++) {
      o_lo = mfma32(pa[ks], vl[ks], o_lo);
      o_hi = mfma32(pa[ks], vh[ks], o_hi);
    }
  };

  const unsigned short* K0 = &K_lds[0][0];
  const unsigned short* K1 = &K_lds[1][0];
  const unsigned short* K2 = &K_lds[2][0];
  const unsigned short* V0 = &V_lds[0][0];
  const unsigned short* V1 = &V_lds[1][0];
  const unsigned short* V2 = &V_lds[2][0];

  // tiles 0..29: tile u (buffer u%3) computes after staging tile u+2 into buffer (u+2)%3.
  for (int it = 0; it < 10; ++it) {
    const int u = it * 3;
    VBAR4; STAGE(dbC); TILE(K0, V0, u * 64);
    VBAR4; STAGE(dbA); TILE(K1, V1, (u + 1) * 64);
    VBAR4; STAGE(dbB); TILE(K2, V2, (u + 2) * 64);
  }
  // tiles 30 (buf 0), 31 (buf 1): no more staging; final tile needs full drain.
  VBAR4; TILE(K0, V0, 30 * 64);
  VBAR0; TILE(K1, V1, 31 * 64);

  const float inv = 1.f / l_run;
#pragma unroll
  for (int r2 = 0; r2 < 16; r2++) {
    const int ro = (r2 & 3) + 8 * (r2 >> 2) + 4 * hi;
    const float rr = __shfl(inv, ro, 64);
    unsigned short* op = At + (size_t)(b * 2048 + q0w + ro) * 512 + h * 64;
    op[q31] = f2bf(o_lo[r2] * rr);
    op[32 + q31] = f2bf(o_hi[r2] * rr);
  }
}

// ---------------- host ----------------
extern "C" void kernel_launch(void* const* d_in, const int* in_sizes, int n_in,
                              void* d_out, int out_size, void* d_ws, size_t ws_size,
                              hipStream_t stream) {
  const float* query = (const float*)d_in[0];
  const float* key   = (const float*)d_in[1];
  const float* value = (const float*)d_in[2];
  const float* Wq = (const float*)d_in[3];
  const float* bq = (const float*)d_in[4];
  const float* Wk = (const float*)d_in[5];
  const float* bk = (const float*)d_in[6];
  const float* Wv = (const float*)d_in[7];
  const float* bv = (const float*)d_in[8];
  const float* Wo = (const float*)d_in[9];
  const float* bo = (const float*)d_in[10];
  const float* rel = (const float*)d_in[11];

  char* ws = (char*)d_ws;
  unsigned short* base = (unsigned short*)ws;       // xq xk xv | wq wk wv wo | ...
  unsigned short* wo = base + 3 * SZX_E + 3 * SZW_E;
  unsigned short* Qp = base + 3 * SZX_E + 4 * SZW_E;
  unsigned short* Kp = Qp + SZX_E;
  unsigned short* Vt = Kp + SZX_E;
  unsigned short* At = Vt + SZX_E;

  cvt_all<<<dim3(13312), dim3(256), 0, stream>>>(query, key, value, Wq, Wk, Wv, Wo, base);

  dim3 blk(256);
  gemm_qkv<<<dim3(4, 64, 3), blk, 0, stream>>>(base, bq, bk, bv, Qp);

  attn_kernel<<<dim3(512), blk, 0, stream>>>(Qp, Kp, Vt, rel, At);

  gemm_o<<<dim3(4, 64), blk, 0, stream>>>(At, wo, bo, (float*)d_out);
}